// Round 9
// baseline (92.132 us; speedup 1.0000x reference)
//
#include <hip/hip_runtime.h>
#include <cstdint>
#include <cstddef>

#define CCH   512
#define FSCOPE 27
#define HWSP  3136
#define NBATCH 16
#define NCOL  (NBATCH*HWSP)   // 50176

#define BMT 64                // rows per block (H panel in LDS, 64KB)
#define BCT 256               // cols per block (8 waves x 32 cols)

#define PI_F 3.14159265358979323846f

typedef __bf16 bf16x8 __attribute__((ext_vector_type(8)));
typedef float  f32x4  __attribute__((ext_vector_type(4)));

static __device__ __forceinline__ unsigned short f2bf(float f) {
  unsigned u = __builtin_bit_cast(unsigned, f);
  unsigned r = 0x7FFFu + ((u >> 16) & 1u);
  return (unsigned short)((u + r) >> 16);
}

// ---- kernel 1 (fused fk + inverse DFT, parallel over d):
__global__ __launch_bounds__(512)
void k_h2(const float* __restrict__ w, float* __restrict__ h) {
  __shared__ float red[8];
  const int d = blockIdx.x;
  const int m = threadIdx.x;

  float re = 1.0f, im = 0.0f;
  #pragma unroll
  for (int j = 0; j < FSCOPE; ++j) {
    int t = (m * (j - FSCOPE/2)) % CCH;
    if (t < 0) t += CCH;
    float ang = (2.0f * PI_F / CCH) * (float)t;
    float s, c;
    sincosf(ang, &s, &c);
    float wj = w[j];
    re -= wj * c;
    im += wj * s;
  }

  int t = (m * d) & (CCH - 1);
  float ang = (2.0f * PI_F / CCH) * (float)t;
  float s, c;
  sincosf(ang, &s, &c);
  float inv = 1.0f / (re * re + im * im);
  float term = (c * re + s * im) * inv;

  #pragma unroll
  for (int off = 32; off > 0; off >>= 1)
    term += __shfl_down(term, off, 64);

  const int lane = m & 63, wv = m >> 6;
  if (lane == 0) red[wv] = term;
  __syncthreads();
  if (m == 0) {
    float tot = 0.f;
    #pragma unroll
    for (int i = 0; i < 8; ++i) tot += red[i];
    h[d] = tot / (float)CCH;
  }
}

// ---- kernel 2: H[m][k] = bf16( h[(m-k) mod 512] ), row-major 512x512
__global__ void k_buildH(const float* __restrict__ h, unsigned short* __restrict__ Hm) {
  int m = blockIdx.x;
  for (int k = threadIdx.x; k < CCH; k += blockDim.x) {
    Hm[m*CCH + k] = f2bf(h[(m - k) & (CCH - 1)]);
  }
}

// LOADB: raw f32 X loads for K-step ks into named buffer (reg prefetch)
// (kq*8*HWSP folded into xb at init)
#define LOADB(ks, buf)                                              \
  { _Pragma("unroll")                                               \
    for (int cs = 0; cs < 2; ++cs) {                                \
      _Pragma("unroll")                                             \
      for (int j = 0; j < 8; ++j)                                   \
        buf[cs][j] = xb[cs][(size_t)((ks) * 32 + j) * HWSP];        \
    } }

// COMPUTE: cvt buffer -> bf16 frags, 4 swizzled ds_reads, 8 MFMAs
#define COMPUTE(ks, buf)                                                      \
  { bf16x8 pb0, pb1;                                                          \
    { union { __bf16 hh[8]; bf16x8 v; } u;                                    \
      _Pragma("unroll")                                                       \
      for (int j = 0; j < 8; ++j) u.hh[j] = (__bf16)buf[0][j];                \
      pb0 = u.v; }                                                            \
    { union { __bf16 hh[8]; bf16x8 v; } u;                                    \
      _Pragma("unroll")                                                       \
      for (int j = 0; j < 8; ++j) u.hh[j] = (__bf16)buf[1][j];                \
      pb1 = u.v; }                                                            \
    const int kb_ = (((ks) >> 1) << 7) + ((((((ks) & 1) << 2) | kq) ^ rw) << 4); \
    _Pragma("unroll")                                                         \
    for (int fm = 0; fm < 4; ++fm) {                                          \
      bf16x8 af = *reinterpret_cast<const bf16x8*>(Al + aBase[fm] + kb_);     \
      acc[fm][0] = __builtin_amdgcn_mfma_f32_16x16x32_bf16(af, pb0, acc[fm][0], 0, 0, 0); \
      acc[fm][1] = __builtin_amdgcn_mfma_f32_16x16x32_bf16(af, pb1, acc[fm][1], 0, 0, 0); \
    } }

// ---- kernel 3: Y = H * X, barrier-free streaming GEMM.
// Block: H rows [m0,m0+64) in 64KB LDS (loaded once, then read-only);
// 8 waves x 32 cols each stream X from global, 3-buffer distance-2 prefetch.
// grid = 8 m-tiles * 196 col-tiles = 1568 blocks, 512 threads.
// 64KB LDS -> 2 blocks/CU (16 waves/CU, 4/SIMD); launch_bounds caps VGPR<=128.
__global__ __launch_bounds__(512, 4)
void k_gemm(const float* __restrict__ X, const unsigned short* __restrict__ Hm,
            float* __restrict__ Y) {
  __shared__ __align__(16) unsigned char Al[BMT * 1024];   // 64 KB

  const int tid  = threadIdx.x;
  const int lane = tid & 63;
  const int w    = tid >> 6;       // 0..7
  const int r15  = lane & 15;
  const int kq   = lane >> 4;      // 0..3
  const int rw   = r15 & 7;

  // XCD-aware swizzle (1568 = 8 * 196, bijective); m-tile fastest so the 8
  // blocks sharing a col-tile (same X cols) land on the same XCD's L2.
  int bid = blockIdx.x;
  int cpx = gridDim.x >> 3;        // 196
  int swz = (bid & 7) * cpx + (bid >> 3);
  const int tm = swz & 7;          // 0..7
  const int tc = swz >> 3;         // 0..195
  const int m0 = tm * BMT;
  const int j0 = tc * BCT;

  // ---- prologue: H panel -> LDS via global_load_lds.
  // Wave-uniform dst row*1024 (+lane*16 by HW); lane's global chunk
  // pre-swizzled: cgl = (lane&56)|((lane&7)^(row&7))  (involution).
  #pragma unroll
  for (int i = 0; i < 8; ++i) {
    int r = w * 8 + i;
    int cgl = (lane & 56) | ((lane & 7) ^ (r & 7));
    const unsigned short* src = Hm + (size_t)(m0 + r) * CCH + cgl * 8;
    __builtin_amdgcn_global_load_lds(
        (const __attribute__((address_space(1))) void*)src,
        (__attribute__((address_space(3))) void*)(Al + r * 1024), 16, 0, 0);
  }
  __syncthreads();   // the only barrier; LDS read-only afterwards

  // a-frag row bases (swizzled chunk offset added per K-step)
  int aBase[4];
  #pragma unroll
  for (int fm = 0; fm < 4; ++fm) aBase[fm] = (fm * 16 + r15) * 1024;

  // per-lane column base pointers (cols may straddle batch boundary);
  // kq's k-offset folded into xb.
  const float* xb[2];
  float*       yb[2];
  #pragma unroll
  for (int cs = 0; cs < 2; ++cs) {
    int colg = j0 + w * 32 + cs * 16 + r15;
    int n = colg / HWSP;
    int s = colg - n * HWSP;
    xb[cs] = X + (size_t)n * (CCH * (size_t)HWSP) + s + (size_t)(kq * 8) * HWSP;
    yb[cs] = Y + (size_t)n * (CCH * (size_t)HWSP) + s;
  }

  f32x4 acc[4][2];
  #pragma unroll
  for (int i = 0; i < 4; ++i) {
    acc[i][0] = (f32x4){0.f, 0.f, 0.f, 0.f};
    acc[i][1] = (f32x4){0.f, 0.f, 0.f, 0.f};
  }

  // 3 named buffers, step s lives in buffer (s mod 3): A=0, B=1, C=2.
  float bufA[2][8], bufB[2][8], bufC[2][8];
  LOADB(0, bufA);
  LOADB(1, bufB);

  for (int kp = 0; kp < 4; ++kp) {           // steps 3kp .. 3kp+2 (0..11)
    const int t = kp * 3;
    LOADB(t + 2, bufC);  COMPUTE(t,     bufA);
    LOADB(t + 3, bufA);  COMPUTE(t + 1, bufB);
    LOADB(t + 4, bufB);  COMPUTE(t + 2, bufC);
  }
  // epilogue steps 12..15 (loads 14,15 only)
  LOADB(14, bufC);  COMPUTE(12, bufA);
  LOADB(15, bufA);  COMPUTE(13, bufB);
  COMPUTE(14, bufC);
  COMPUTE(15, bufA);

  // ---- epilogue: C/D layout col = lane&15, row = kq*4 + r (m89/m91)
  #pragma unroll
  for (int fm = 0; fm < 4; ++fm) {
    #pragma unroll
    for (int cs = 0; cs < 2; ++cs) {
      float* yp = yb[cs] + (size_t)(m0 + fm * 16 + kq * 4) * HWSP;
      #pragma unroll
      for (int r = 0; r < 4; ++r)
        yp[(size_t)r * HWSP] = acc[fm][cs][r];
    }
  }
}

extern "C" void kernel_launch(void* const* d_in, const int* in_sizes, int n_in,
                              void* d_out, int out_size, void* d_ws, size_t ws_size,
                              hipStream_t stream) {
  const float* X = (const float*)d_in[0];   // [16,512,56,56] f32
  const float* w = (const float*)d_in[1];   // [27] f32
  float* Y = (float*)d_out;

  float* h           = (float*)d_ws;                                // 2 KB
  unsigned short* Hm = (unsigned short*)((char*)d_ws + 4096);       // 512 KB

  k_h2    <<<CCH, 512, 0, stream>>>(w, h);
  k_buildH<<<CCH, 256, 0, stream>>>(h, Hm);

  const int nblk = (CCH / BMT) * (NCOL / BCT);   // 8 * 196 = 1568
  k_gemm  <<<nblk, 512, 0, stream>>>(X, Hm, Y);
}

// Round 10
// 80.862 us; speedup vs baseline: 1.1394x; 1.1394x over previous
//
#include <hip/hip_runtime.h>
#include <cstdint>
#include <cstddef>

#define CCH   512
#define FSCOPE 27
#define HWSP  3136
#define NBATCH 16
#define NCOL  (NBATCH*HWSP)   // 50176

#define BMT 64                // rows per block (H panel in LDS, 64KB)
#define BCT 256               // cols per block (8 waves x 32 cols)

#define PI_F 3.14159265358979323846f

typedef __bf16 bf16x8 __attribute__((ext_vector_type(8)));
typedef float  f32x4  __attribute__((ext_vector_type(4)));

static __device__ __forceinline__ unsigned short f2bf(float f) {
  unsigned u = __builtin_bit_cast(unsigned, f);
  unsigned r = 0x7FFFu + ((u >> 16) & 1u);
  return (unsigned short)((u + r) >> 16);
}

// ---- kernel 1 (fused fk + inverse DFT, parallel over d):
__global__ __launch_bounds__(512)
void k_h2(const float* __restrict__ w, float* __restrict__ h) {
  __shared__ float red[8];
  const int d = blockIdx.x;
  const int m = threadIdx.x;

  float re = 1.0f, im = 0.0f;
  #pragma unroll
  for (int j = 0; j < FSCOPE; ++j) {
    int t = (m * (j - FSCOPE/2)) % CCH;
    if (t < 0) t += CCH;
    float ang = (2.0f * PI_F / CCH) * (float)t;
    float s, c;
    sincosf(ang, &s, &c);
    float wj = w[j];
    re -= wj * c;
    im += wj * s;
  }

  int t = (m * d) & (CCH - 1);
  float ang = (2.0f * PI_F / CCH) * (float)t;
  float s, c;
  sincosf(ang, &s, &c);
  float inv = 1.0f / (re * re + im * im);
  float term = (c * re + s * im) * inv;

  #pragma unroll
  for (int off = 32; off > 0; off >>= 1)
    term += __shfl_down(term, off, 64);

  const int lane = m & 63, wv = m >> 6;
  if (lane == 0) red[wv] = term;
  __syncthreads();
  if (m == 0) {
    float tot = 0.f;
    #pragma unroll
    for (int i = 0; i < 8; ++i) tot += red[i];
    h[d] = tot / (float)CCH;
  }
}

// ---- kernel 2: H[m][k] = bf16( h[(m-k) mod 512] ), row-major 512x512
__global__ void k_buildH(const float* __restrict__ h, unsigned short* __restrict__ Hm) {
  int m = blockIdx.x;
  for (int k = threadIdx.x; k < CCH; k += blockDim.x) {
    Hm[m*CCH + k] = f2bf(h[(m - k) & (CCH - 1)]);
  }
}

// LOADB: raw f32 X loads for K-step ks into named buffer (reg prefetch)
// (kq*8*HWSP folded into xb at init)
#define LOADB(ks, buf)                                              \
  { _Pragma("unroll")                                               \
    for (int cs = 0; cs < 2; ++cs) {                                \
      _Pragma("unroll")                                             \
      for (int j = 0; j < 8; ++j)                                   \
        buf[cs][j] = xb[cs][(size_t)((ks) * 32 + j) * HWSP];        \
    } }

// COMPUTE: cvt buffer -> bf16 frags, 4 swizzled ds_reads, 8 MFMAs
#define COMPUTE(ks, buf)                                                      \
  { bf16x8 pb0, pb1;                                                          \
    { union { __bf16 hh[8]; bf16x8 v; } u;                                    \
      _Pragma("unroll")                                                       \
      for (int j = 0; j < 8; ++j) u.hh[j] = (__bf16)buf[0][j];                \
      pb0 = u.v; }                                                            \
    { union { __bf16 hh[8]; bf16x8 v; } u;                                    \
      _Pragma("unroll")                                                       \
      for (int j = 0; j < 8; ++j) u.hh[j] = (__bf16)buf[1][j];                \
      pb1 = u.v; }                                                            \
    const int kb_ = (((ks) >> 1) << 7) + ((((((ks) & 1) << 2) | kq) ^ rw) << 4); \
    _Pragma("unroll")                                                         \
    for (int fm = 0; fm < 4; ++fm) {                                          \
      bf16x8 af = *reinterpret_cast<const bf16x8*>(Al + aBase[fm] + kb_);     \
      acc[fm][0] = __builtin_amdgcn_mfma_f32_16x16x32_bf16(af, pb0, acc[fm][0], 0, 0, 0); \
      acc[fm][1] = __builtin_amdgcn_mfma_f32_16x16x32_bf16(af, pb1, acc[fm][1], 0, 0, 0); \
    } }

// ---- kernel 3: Y = H * X, barrier-free streaming GEMM.
// Block: H rows [m0,m0+64) in 64KB LDS (loaded once, then read-only);
// 8 waves x 32 cols each stream X from global, 3-buffer distance-2 prefetch.
// grid = 8 m-tiles * 196 col-tiles = 1568 blocks, 512 threads.
// 64KB LDS -> 2 blocks/CU; launch_bounds(512,2) leaves VGPR room (~100 needed;
// r9's (512,4) forced 64 VGPR -> scratch spills -> 148us).
__global__ __launch_bounds__(512, 2)
void k_gemm(const float* __restrict__ X, const unsigned short* __restrict__ Hm,
            float* __restrict__ Y) {
  __shared__ __align__(16) unsigned char Al[BMT * 1024];   // 64 KB

  const int tid  = threadIdx.x;
  const int lane = tid & 63;
  const int w    = tid >> 6;       // 0..7
  const int r15  = lane & 15;
  const int kq   = lane >> 4;      // 0..3
  const int rw   = r15 & 7;

  // XCD-aware swizzle (1568 = 8 * 196, bijective); m-tile fastest so the 8
  // blocks sharing a col-tile (same X cols) land on the same XCD's L2.
  int bid = blockIdx.x;
  int cpx = gridDim.x >> 3;        // 196
  int swz = (bid & 7) * cpx + (bid >> 3);
  const int tm = swz & 7;          // 0..7
  const int tc = swz >> 3;         // 0..195
  const int m0 = tm * BMT;
  const int j0 = tc * BCT;

  // ---- prologue: H panel -> LDS via global_load_lds.
  // Wave-uniform dst row*1024 (+lane*16 by HW); lane's global chunk
  // pre-swizzled: cgl = (lane&56)|((lane&7)^(row&7))  (involution).
  #pragma unroll
  for (int i = 0; i < 8; ++i) {
    int r = w * 8 + i;
    int cgl = (lane & 56) | ((lane & 7) ^ (r & 7));
    const unsigned short* src = Hm + (size_t)(m0 + r) * CCH + cgl * 8;
    __builtin_amdgcn_global_load_lds(
        (const __attribute__((address_space(1))) void*)src,
        (__attribute__((address_space(3))) void*)(Al + r * 1024), 16, 0, 0);
  }
  __syncthreads();   // the only barrier; LDS read-only afterwards

  // a-frag row bases (swizzled chunk offset added per K-step)
  int aBase[4];
  #pragma unroll
  for (int fm = 0; fm < 4; ++fm) aBase[fm] = (fm * 16 + r15) * 1024;

  // per-lane column base pointers (cols may straddle batch boundary);
  // kq's k-offset folded into xb.
  const float* xb[2];
  float*       yb[2];
  #pragma unroll
  for (int cs = 0; cs < 2; ++cs) {
    int colg = j0 + w * 32 + cs * 16 + r15;
    int n = colg / HWSP;
    int s = colg - n * HWSP;
    xb[cs] = X + (size_t)n * (CCH * (size_t)HWSP) + s + (size_t)(kq * 8) * HWSP;
    yb[cs] = Y + (size_t)n * (CCH * (size_t)HWSP) + s;
  }

  f32x4 acc[4][2];
  #pragma unroll
  for (int i = 0; i < 4; ++i) {
    acc[i][0] = (f32x4){0.f, 0.f, 0.f, 0.f};
    acc[i][1] = (f32x4){0.f, 0.f, 0.f, 0.f};
  }

  // 3 named buffers, step s lives in buffer (s mod 3): A=0, B=1, C=2.
  float bufA[2][8], bufB[2][8], bufC[2][8];
  LOADB(0, bufA);
  LOADB(1, bufB);

  for (int kp = 0; kp < 4; ++kp) {           // steps 3kp .. 3kp+2 (0..11)
    const int t = kp * 3;
    LOADB(t + 2, bufC);  COMPUTE(t,     bufA);
    LOADB(t + 3, bufA);  COMPUTE(t + 1, bufB);
    LOADB(t + 4, bufB);  COMPUTE(t + 2, bufC);
  }
  // epilogue steps 12..15 (loads 14,15 only)
  LOADB(14, bufC);  COMPUTE(12, bufA);
  LOADB(15, bufA);  COMPUTE(13, bufB);
  COMPUTE(14, bufC);
  COMPUTE(15, bufA);

  // ---- epilogue: C/D layout col = lane&15, row = kq*4 + r (m89/m91)
  #pragma unroll
  for (int fm = 0; fm < 4; ++fm) {
    #pragma unroll
    for (int cs = 0; cs < 2; ++cs) {
      float* yp = yb[cs] + (size_t)(m0 + fm * 16 + kq * 4) * HWSP;
      #pragma unroll
      for (int r = 0; r < 4; ++r)
        yp[(size_t)r * HWSP] = acc[fm][cs][r];
    }
  }
}

extern "C" void kernel_launch(void* const* d_in, const int* in_sizes, int n_in,
                              void* d_out, int out_size, void* d_ws, size_t ws_size,
                              hipStream_t stream) {
  const float* X = (const float*)d_in[0];   // [16,512,56,56] f32
  const float* w = (const float*)d_in[1];   // [27] f32
  float* Y = (float*)d_out;

  float* h           = (float*)d_ws;                                // 2 KB
  unsigned short* Hm = (unsigned short*)((char*)d_ws + 4096);       // 512 KB

  k_h2    <<<CCH, 512, 0, stream>>>(w, h);
  k_buildH<<<CCH, 256, 0, stream>>>(h, Hm);

  const int nblk = (CCH / BMT) * (NCOL / BCT);   // 8 * 196 = 1568
  k_gemm  <<<nblk, 512, 0, stream>>>(X, Hm, Y);
}

// Round 11
// 59.822 us; speedup vs baseline: 1.5401x; 1.3517x over previous
//
#include <hip/hip_runtime.h>
#include <cstdint>
#include <cstddef>

#define CCH   512
#define FSCOPE 27
#define HWSP  3136
#define NBATCH 16
#define NCOL  (NBATCH*HWSP)   // 50176

#define BM 128
#define BN 128
#define BK 64
#define NKT (CCH/BK)          // 8

#define PI_F 3.14159265358979323846f

typedef __bf16 bf16x8 __attribute__((ext_vector_type(8)));
typedef float  f32x4  __attribute__((ext_vector_type(4)));

static __device__ __forceinline__ unsigned short f2bf(float f) {
  unsigned u = __builtin_bit_cast(unsigned, f);
  unsigned r = 0x7FFFu + ((u >> 16) & 1u);
  return (unsigned short)((u + r) >> 16);
}

// ---- kernel 1 (fused fk + inverse DFT, parallel over d):
__global__ __launch_bounds__(512)
void k_h2(const float* __restrict__ w, float* __restrict__ h) {
  __shared__ float red[8];
  const int d = blockIdx.x;
  const int m = threadIdx.x;

  float re = 1.0f, im = 0.0f;
  #pragma unroll
  for (int j = 0; j < FSCOPE; ++j) {
    int t = (m * (j - FSCOPE/2)) % CCH;
    if (t < 0) t += CCH;
    float ang = (2.0f * PI_F / CCH) * (float)t;
    float s, c;
    sincosf(ang, &s, &c);
    float wj = w[j];
    re -= wj * c;
    im += wj * s;
  }

  int t = (m * d) & (CCH - 1);
  float ang = (2.0f * PI_F / CCH) * (float)t;
  float s, c;
  sincosf(ang, &s, &c);
  float inv = 1.0f / (re * re + im * im);
  float term = (c * re + s * im) * inv;

  #pragma unroll
  for (int off = 32; off > 0; off >>= 1)
    term += __shfl_down(term, off, 64);

  const int lane = m & 63, wv = m >> 6;
  if (lane == 0) red[wv] = term;
  __syncthreads();
  if (m == 0) {
    float tot = 0.f;
    #pragma unroll
    for (int i = 0; i < 8; ++i) tot += red[i];
    h[d] = tot / (float)CCH;
  }
}

// ---- kernel 2: H[m][k] = bf16( h[(m-k) mod 512] ), row-major 512x512
__global__ void k_buildH(const float* __restrict__ h, unsigned short* __restrict__ Hm) {
  int m = blockIdx.x;
  for (int k = threadIdx.x; k < CCH; k += blockDim.x) {
    Hm[m*CCH + k] = f2bf(h[(m - k) & (CCH - 1)]);
  }
}

// ---- kernel 3: Y = H * X — r3 structure + A-dbuf + hoisted prefetch.
// grid = 4 m-tiles * 392 col-tiles = 1568 blocks, 256 threads (4 waves)
// LDS 48KB: A0@0 (16K), A1@16K, B@32K (16K) -> 3 blocks/CU.
// Per iter: issue DMA-A(t+1)->A[nxt] + load bv(t+1); compute(t); sync1
// (drains DMA, ~overlapped); writeB(t+1); sync2.
__global__ __launch_bounds__(256)
void k_gemm(const float* __restrict__ X, const unsigned short* __restrict__ Hm,
            float* __restrict__ Y) {
  __shared__ __align__(16) unsigned char lds[49152];

  const int tid  = threadIdx.x;
  const int lane = tid & 63;
  const int w    = tid >> 6;

  // XCD-aware swizzle (1568 = 8 * 196, exact)
  int bid = blockIdx.x;
  int cpx = gridDim.x >> 3;
  int swz = (bid & 7) * cpx + (bid >> 3);
  const int tm = swz & 3;
  const int tc = swz >> 2;

  const int m0 = tm * BM;
  const int j0 = tc * BN;

  unsigned char* Bl = lds + 32768;

  // B staging mapping: thread -> 4 cols (float4) x 8 k's
  const int fg = tid & 31;
  const int kg = tid >> 5;
  const int jb = j0 + fg*4;
  const int nb = jb / HWSP;      // float4 never crosses batch (3136 % 4 == 0)
  const int sb = jb - nb * HWSP;
  const float* Xb = X + (size_t)nb * (CCH*(size_t)HWSP) + sb;

  // B swizzle: g(col) = (col&7) ^ ((col>>3)&7); slot = kq ^ g(col).
  int wrOff[4];
  #pragma unroll
  for (int c = 0; c < 4; ++c) {
    int col = fg*4 + c;
    int g = (col & 7) ^ ((col >> 3) & 7);
    wrOff[c] = col*128 + (((kg ^ g) & 7) << 4);
  }

  const int wr = w >> 1, wc = w & 1;   // wave -> 64x64 quadrant
  int aBase[4], aSw[4], bBase[4], bSw[4];
  #pragma unroll
  for (int fm = 0; fm < 4; ++fm) {
    int m = wr*64 + fm*16 + (lane & 15);
    aBase[fm] = m*128;
    aSw[fm]   = (m & 7) << 4;
  }
  #pragma unroll
  for (int fn = 0; fn < 4; ++fn) {
    int col = wc*64 + fn*16 + (lane & 15);
    bBase[fn] = col*128;
    bSw[fn]   = ((col & 7) ^ ((col >> 3) & 7)) << 4;
  }

  // A DMA lane mapping (r3 verbatim): wave-uniform dst, pre-swizzled src
  const int aRow = lane >> 3;          // +8 rows per i
  const int aChk = lane & 7;

  f32x4 acc[4][4];
  #pragma unroll
  for (int i = 0; i < 4; ++i)
    #pragma unroll
    for (int j = 0; j < 4; ++j)
      acc[i][j] = (f32x4){0.f, 0.f, 0.f, 0.f};

  float4 bv[8];

  // ---- prologue: DMA A(0) -> A0, load bv(0), publish B(0)
  #pragma unroll
  for (int i = 0; i < 4; ++i) {
    int m0w = w*32 + i*8;
    int m   = m0w + aRow;
    const unsigned short* src =
        Hm + (size_t)(m0 + m) * CCH + 8*(aChk ^ (m & 7));
    __builtin_amdgcn_global_load_lds(
        (const __attribute__((address_space(1))) void*)src,
        (__attribute__((address_space(3))) void*)(lds + m0w*128), 16, 0, 0);
  }
  #pragma unroll
  for (int kk = 0; kk < 8; ++kk)
    bv[kk] = *reinterpret_cast<const float4*>(Xb + (size_t)(kg*8 + kk) * HWSP);
  __syncthreads();   // drains DMA(0) + bv(0)
  #pragma unroll
  for (int c = 0; c < 4; ++c) {
    union { __bf16 h[8]; int4 v; } u;
    #pragma unroll
    for (int kk = 0; kk < 8; ++kk) {
      float f = (c==0) ? bv[kk].x : (c==1) ? bv[kk].y : (c==2) ? bv[kk].z : bv[kk].w;
      u.h[kk] = (__bf16)f;
    }
    *reinterpret_cast<int4*>(Bl + wrOff[c]) = u.v;
  }
  __syncthreads();   // B(0) visible

  // ---- main loop
  for (int kt = 0; kt < NKT; ++kt) {
    const int aoffC = (kt & 1) * 16384;
    const int aoffN = 16384 - aoffC;

    // issue next tile's A-DMA and B-loads BEFORE compute (latency overlap)
    if (kt + 1 < NKT) {
      #pragma unroll
      for (int i = 0; i < 4; ++i) {
        int m0w = w*32 + i*8;
        int m   = m0w + aRow;
        const unsigned short* src =
            Hm + (size_t)(m0 + m) * CCH + (kt + 1)*BK + 8*(aChk ^ (m & 7));
        __builtin_amdgcn_global_load_lds(
            (const __attribute__((address_space(1))) void*)src,
            (__attribute__((address_space(3))) void*)(lds + aoffN + m0w*128), 16, 0, 0);
      }
      const float* Xk = Xb + (size_t)((kt + 1)*BK + kg*8) * HWSP;
      #pragma unroll
      for (int kk = 0; kk < 8; ++kk)
        bv[kk] = *reinterpret_cast<const float4*>(Xk + (size_t)kk * HWSP);
    }

    // compute tile kt from A[cur] and B
    #pragma unroll
    for (int ks = 0; ks < 2; ++ks) {
      const int kbyte = ks*64 + ((lane >> 4) << 4);
      bf16x8 af[4], bfr[4];
      #pragma unroll
      for (int fm = 0; fm < 4; ++fm)
        af[fm] = *reinterpret_cast<const bf16x8*>(lds + aoffC + aBase[fm] + (kbyte ^ aSw[fm]));
      #pragma unroll
      for (int fn = 0; fn < 4; ++fn)
        bfr[fn] = *reinterpret_cast<const bf16x8*>(Bl + bBase[fn] + (kbyte ^ bSw[fn]));
      #pragma unroll
      for (int fm = 0; fm < 4; ++fm)
        #pragma unroll
        for (int fn = 0; fn < 4; ++fn)
          acc[fm][fn] = __builtin_amdgcn_mfma_f32_16x16x32_bf16(
              af[fm], bfr[fn], acc[fm][fn], 0, 0, 0);
    }

    __syncthreads();   // sync1: all waves done with B(kt); DMA(kt+1) drained

    if (kt + 1 < NKT) {
      #pragma unroll
      for (int c = 0; c < 4; ++c) {
        union { __bf16 h[8]; int4 v; } u;
        #pragma unroll
        for (int kk = 0; kk < 8; ++kk) {
          float f = (c==0) ? bv[kk].x : (c==1) ? bv[kk].y : (c==2) ? bv[kk].z : bv[kk].w;
          u.h[kk] = (__bf16)f;
        }
        *reinterpret_cast<int4*>(Bl + wrOff[c]) = u.v;
      }
      __syncthreads(); // sync2: B(kt+1) visible
    }
  }

  // epilogue: C/D layout col = lane&15, row = (lane>>4)*4 + r  (m89/m91)
  #pragma unroll
  for (int fn = 0; fn < 4; ++fn) {
    int colg = j0 + wc*64 + fn*16 + (lane & 15);
    int n = colg / HWSP;
    int s = colg - n * HWSP;
    float* Yb = Y + (size_t)n * (CCH*(size_t)HWSP) + s;
    #pragma unroll
    for (int fm = 0; fm < 4; ++fm) {
      int mrow = m0 + wr*64 + fm*16 + ((lane >> 4) << 2);
      #pragma unroll
      for (int r = 0; r < 4; ++r)
        Yb[(size_t)(mrow + r) * HWSP] = acc[fm][fn][r];
    }
  }
}

extern "C" void kernel_launch(void* const* d_in, const int* in_sizes, int n_in,
                              void* d_out, int out_size, void* d_ws, size_t ws_size,
                              hipStream_t stream) {
  const float* X = (const float*)d_in[0];   // [16,512,56,56] f32
  const float* w = (const float*)d_in[1];   // [27] f32
  float* Y = (float*)d_out;

  float* h           = (float*)d_ws;                                // 2 KB
  unsigned short* Hm = (unsigned short*)((char*)d_ws + 4096);       // 512 KB

  k_h2    <<<CCH, 512, 0, stream>>>(w, h);
  k_buildH<<<CCH, 256, 0, stream>>>(h, Hm);

  const int nblk = (CCH/BM) * (NCOL/BN);    // 4 * 392 = 1568
  k_gemm  <<<nblk, 256, 0, stream>>>(X, Hm, Y);
}